// Round 2
// baseline (7605.796 us; speedup 1.0000x reference)
//
#include <hip/hip_runtime.h>
#include <cstdint>

// ---------------- problem constants (fixed by the reference) ----------------
#define NN 100000      // nodes per graph (users == items)
#define EE 3200000     // edges per graph
// RANK=10, ORD=5, N_CONV=32, N_ITER=10, BATCH=65536

typedef unsigned short u16;

constexpr int GSTRIDE = 100032;            // padded per-graph stride for N-length arrays
constexpr int RP_ST   = 100032;            // rowptr per-graph stride (holds N+1)
constexpr size_t NZ = (size_t)NN * 12;     // padded node-feature row: 10 used + 2 pad (48B, 16B aligned)
constexpr size_t NF = (size_t)NN * 60;     // feat: 5 Chebyshev slices x 12
constexpr size_t NX = (size_t)NN * 32;     // conv/LSTM width

// ---------------- workspace layout (bytes) ----------------
constexpr size_t OFF_ROWPTR = 0;                                  // 2 * RP_ST ints (+ flag in spare tail slot)
constexpr size_t OFF_FILL   = OFF_ROWPTR + 2 * (size_t)RP_ST * 4;
constexpr size_t OFF_COUNT  = OFF_FILL   + 2 * (size_t)GSTRIDE * 4;  // reused for f32 weights after k_scan
constexpr size_t OFF_DEG    = OFF_COUNT  + 2 * (size_t)GSTRIDE * 4;
constexpr size_t OFF_DINV   = OFF_DEG    + 2 * (size_t)GSTRIDE * 4;
constexpr size_t OFF_W      = OFF_DINV   + 2 * (size_t)GSTRIDE * 4;  // W,H factors: 2 x NZ floats
constexpr size_t OFF_Z      = OFF_W      + 2 * NZ * 4;               // 2 graphs x 2 ping-pong bufs x NZ
constexpr size_t OFF_FEAT   = OFF_Z      + 4 * NZ * 4;               // 2 x NF
constexpr size_t OFF_X      = OFF_FEAT   + 2 * NF * 4;               // 2 x NX (conv output)
constexpr size_t OFF_H      = OFF_X      + 2 * NX * 4;               // 2 x NX
constexpr size_t OFF_C      = OFF_H      + 2 * NX * 4;               // 2 x NX
constexpr size_t OFF_CEDGE  = OFF_C      + 2 * NX * 4;               // 2 x EE int2 (col, scaled coeff)
constexpr size_t WS_NEED    = OFF_CEDGE  + 2 * (size_t)EE * 8;       // ~209 MB (same as round 1, which ran)

// f32 weight pack layout (into the dead COUNT region after k_scan):
// Wcw 1600 | bcw 32 | Wch 1600 | bch 32 | Wgu 4096 | Ugu 4096 | bgu 128 |
// Wgm 4096 | Ugm 4096 | bgm 128 | Wow 320 | bow 10 | Woh 320 | boh 10   = 20564 floats
constexpr int WOFF_WCW = 0, WOFF_BCW = 1600, WOFF_WCH = 1632, WOFF_BCH = 3232;
constexpr int WOFF_WGU = 3264, WOFF_UGU = 7360, WOFF_BGU = 11456;
constexpr int WOFF_WGM = 11584, WOFF_UGM = 15680, WOFF_BGM = 19776;
constexpr int WOFF_WOW = 19904, WOFF_BOW = 20224, WOFF_WOH = 20234, WOFF_BOH = 20554;
constexpr int WTOTAL = 20564;

__device__ __forceinline__ float sigf(float x) { return 1.f / (1.f + __expf(-x)); }

// dtype-flexible load: bf=1 -> buffer holds bf16, else f32
__device__ __forceinline__ float ldf(const void* p, long long i, int bf) {
  if (bf) return __uint_as_float(((uint32_t)((const u16*)p)[i]) << 16);
  return ((const float*)p)[i];
}
__device__ __forceinline__ u16 f2b(float f) {  // RNE f32 -> bf16 (no NaN in our range)
  uint32_t u = __float_as_uint(f);
  return (u16)((u + 0x7FFFu + ((u >> 16) & 1u)) >> 16);
}

// ---------------- dtype probe ----------------
// ug_val is uniform[0,1) >= 0: if stored as bf16, NO halfword has bit15 set
// (positive bf16 < 2 => bits <= 0x3FFF). If f32, low halfwords are random
// mantissa bits -> bit15 set ~50% of the time. 8192 samples => deterministic.
__global__ __launch_bounds__(256) void k_detect(const u16* __restrict__ uv, int* __restrict__ flag) {
  int t = threadIdx.x;
  uint32_t any = 0;
  for (int j = t; j < 8192; j += 256) any |= (uv[j] & 0x8000u);
  unsigned long long b = __ballot(any != 0);
  if (t == 0) flag[0] = (b == 0ull) ? 1 : 0;  // 1 = bf16 inputs/outputs
}

// ---------------- setup kernels ----------------

// copy W0/H0 into padded fp32 working factors
__global__ __launch_bounds__(256) void k_init(const void* __restrict__ W0, const void* __restrict__ H0,
                                              float* __restrict__ Wws, const int* __restrict__ flag) {
  int t = blockIdx.x * 256 + threadIdx.x;
  if (t >= 2 * NN) return;
  int bf = flag[0];
  int g = (t >= NN) ? 1 : 0;
  int n = t - g * NN;
  const void* src = g ? H0 : W0;
  float* dst = Wws + (size_t)g * NZ + (size_t)n * 12;
#pragma unroll
  for (int r = 0; r < 10; r++) dst[r] = ldf(src, (long long)n * 10 + r, bf);
  dst[10] = 0.f; dst[11] = 0.f;
}

// histogram rows + degree accumulation (both graphs)
__global__ __launch_bounds__(256) void k_hist(const int* __restrict__ ur, const void* __restrict__ uv,
                                              const int* __restrict__ ir, const void* __restrict__ iv,
                                              int* __restrict__ count, float* __restrict__ deg,
                                              const int* __restrict__ flag) {
  int bf = flag[0];
  long long stride = (long long)gridDim.x * blockDim.x;
  for (long long t = (long long)blockIdx.x * blockDim.x + threadIdx.x; t < 2LL * EE; t += stride) {
    int g = (t >= EE) ? 1 : 0;
    int e = (int)(t - (long long)g * EE);
    int row = (g ? ir : ur)[e];
    float v = ldf(g ? iv : uv, e, bf);
    atomicAdd(&count[g * GSTRIDE + row], 1);
    atomicAdd(&deg[g * GSTRIDE + row], v);
  }
}

// single-block-per-graph exclusive scan -> rowptr, fill copy, dinv
__global__ __launch_bounds__(1024) void k_scan(const int* __restrict__ count, int* __restrict__ rowptr,
                                               int* __restrict__ fill, const float* __restrict__ deg,
                                               float* __restrict__ dinv) {
  constexpr int CH = 98;  // ceil(100000/1024)
  int g = blockIdx.x, tid = threadIdx.x;
  const int* cnt = count + g * GSTRIDE;
  int base = tid * CH;
  int s = 0;
  for (int j = 0; j < CH; j++) { int i = base + j; if (i < NN) s += cnt[i]; }
  __shared__ int sh[1024];
  sh[tid] = s;
  __syncthreads();
  for (int off = 1; off < 1024; off <<= 1) {
    int v = (tid >= off) ? sh[tid - off] : 0;
    __syncthreads();
    sh[tid] += v;
    __syncthreads();
  }
  int run = sh[tid] - s;  // exclusive prefix
  int* rp = rowptr + g * RP_ST;
  int* fl = fill + g * GSTRIDE;
  const float* dg = deg + g * GSTRIDE;
  float* dv = dinv + g * GSTRIDE;
  for (int j = 0; j < CH; j++) {
    int i = base + j;
    if (i >= NN) break;
    rp[i] = run; fl[i] = run; run += cnt[i];
    float d = dg[i];
    dv[i] = (d > 0.f) ? rsqrtf(d) : 0.f;
  }
  if (tid == 1023) rp[NN] = run;  // == EE
}

// scatter edges into CSR with fully-normalized coefficient c = val*dinv[row]*dinv[col]
__global__ __launch_bounds__(256) void k_scatter(const int* __restrict__ ur, const int* __restrict__ uc,
                                                 const void* __restrict__ uv, const int* __restrict__ ir,
                                                 const int* __restrict__ ic, const void* __restrict__ iv,
                                                 const float* __restrict__ dinv, int* __restrict__ fill,
                                                 int2* __restrict__ cedge, const int* __restrict__ flag) {
  int bf = flag[0];
  long long stride = (long long)gridDim.x * blockDim.x;
  for (long long t = (long long)blockIdx.x * blockDim.x + threadIdx.x; t < 2LL * EE; t += stride) {
    int g = (t >= EE) ? 1 : 0;
    int e = (int)(t - (long long)g * EE);
    int row = (g ? ir : ur)[e];
    int col = (g ? ic : uc)[e];
    float v = ldf(g ? iv : uv, e, bf);
    const float* dv = dinv + g * GSTRIDE;
    float c = v * dv[row] * dv[col];
    int pos = atomicAdd(&fill[g * GSTRIDE + row], 1);
    cedge[(size_t)g * EE + pos] = make_int2(col, __float_as_int(c));
  }
}

// convert the 14 small weight arrays to one packed f32 region
struct P14 { const void* p[14]; };
__global__ __launch_bounds__(256) void k_cvtw(P14 w, float* __restrict__ dst, const int* __restrict__ flag) {
  int t = blockIdx.x * 256 + threadIdx.x;
  if (t >= WTOTAL) return;
  int bf = flag[0];
  const int sz[14] = {1600, 32, 1600, 32, 4096, 4096, 128, 4096, 4096, 128, 320, 10, 320, 10};
  int off = 0;
#pragma unroll
  for (int s = 0; s < 14; s++) {
    if (t < off + sz[s]) { dst[t] = ldf(w.p[s], t - off, bf); return; }
    off += sz[s];
  }
}

// write T0 = W into feat slice 0 and Z(buf0) = W (UNSCALED — c_e carries all normalization)
__global__ __launch_bounds__(256) void k_prep(const float* __restrict__ Wws, float* __restrict__ feat,
                                              float* __restrict__ Z) {
  int t = blockIdx.x * 256 + threadIdx.x;
  if (t >= 2 * NN) return;
  int g = (t >= NN) ? 1 : 0;
  int n = t - g * NN;
  const float* w = Wws + (size_t)g * NZ + (size_t)n * 12;
  float* f = feat + (size_t)g * NF + (size_t)n * 60;
  float* z = Z + (size_t)g * 2 * NZ + (size_t)n * 12;  // ping-pong buffer 0
#pragma unroll
  for (int r = 0; r < 10; r++) { float x = w[r]; f[r] = x; z[r] = x; }
}

// ---------------- Chebyshev step ----------------
// M = D^-1/2 A D^-1/2 is baked into cedge coeffs. L(Y) = Y - M·Y.
// T1 = T0 - M·T0 ; T_K = 2*(T_{K-1} - M·T_{K-1}) - T_{K-2}.
// Z holds UNSCALED T_{K-1}, double-buffered by K parity. 4 lanes per row.
template <int K>
__global__ __launch_bounds__(256) void k_cheb(const int* __restrict__ rowptr, const int2* __restrict__ cedge,
                                              float* __restrict__ feat, float* __restrict__ Z) {
  constexpr int NBG = (NN + 63) / 64;  // 1563 blocks/graph, 64 rows/block
  int b = blockIdx.x;
  int g = (b >= NBG) ? 1 : 0;
  b -= g * NBG;
  int tid = threadIdx.x;
  int l = tid & 3;
  int row = b * 64 + (tid >> 2);
  const float* Zin = Z + ((size_t)g * 2 + ((K - 1) & 1)) * NZ;
  float* Zout      = Z + ((size_t)g * 2 + (K & 1)) * NZ;
  float acc[10];
#pragma unroll
  for (int r = 0; r < 10; r++) acc[r] = 0.f;
  if (row < NN) {
    const int* rp = rowptr + g * RP_ST;
    int e1 = rp[row + 1];
    const int2* ce = cedge + (size_t)g * EE;
    for (int e = rp[row] + l; e < e1; e += 4) {
      int2 ec = ce[e];
      float c = __int_as_float(ec.y);
      const float4* zp = (const float4*)(Zin + (size_t)ec.x * 12);
      float4 za = zp[0], zb = zp[1], zc = zp[2];
      acc[0] += c * za.x; acc[1] += c * za.y; acc[2] += c * za.z; acc[3] += c * za.w;
      acc[4] += c * zb.x; acc[5] += c * zb.y; acc[6] += c * zb.z; acc[7] += c * zb.w;
      acc[8] += c * zc.x; acc[9] += c * zc.y;
    }
  }
#pragma unroll
  for (int r = 0; r < 10; r++) {
    acc[r] += __shfl_xor(acc[r], 1);
    acc[r] += __shfl_xor(acc[r], 2);
  }
  if (l == 0 && row < NN) {
    float* frow = feat + (size_t)g * NF + (size_t)row * 60;
    float* zrow = Zout + (size_t)row * 12;
#pragma unroll
    for (int r = 0; r < 10; r++) {
      float tprev = frow[(K - 1) * 12 + r];
      float t = tprev - acc[r];           // L(T_{K-1})
      if constexpr (K >= 2) t = 2.f * t - frow[(K - 2) * 12 + r];
      frow[K * 12 + r] = t;
      if constexpr (K < 4) zrow[r] = t;   // K=4's Z never consumed
    }
  }
  (void)Zout;
}

// ---------------- conv: x = relu(feat[50] @ Wc[50x32] + bc) ----------------
__global__ __launch_bounds__(256) void k_conv(const float* __restrict__ feat, float* __restrict__ X,
                                              const float* __restrict__ wts) {
  constexpr int NB = (NN + 255) / 256;  // 391
  int g = (blockIdx.x >= NB) ? 1 : 0;
  int n = (blockIdx.x - g * NB) * 256 + threadIdx.x;
  if (n >= NN) return;
  const float* Wc = wts + (g ? WOFF_WCH : WOFF_WCW);
  const float* bc = wts + (g ? WOFF_BCH : WOFF_BCW);
  const float* frow = feat + (size_t)g * NF + (size_t)n * 60;
  float acc[32];
#pragma unroll
  for (int o = 0; o < 32; o++) acc[o] = bc[o];
#pragma unroll
  for (int k = 0; k < 5; k++) {
    const float4* f4 = (const float4*)(frow + k * 12);
    float4 a = f4[0], b2 = f4[1], c2 = f4[2];
    float fv[10] = {a.x, a.y, a.z, a.w, b2.x, b2.y, b2.z, b2.w, c2.x, c2.y};
#pragma unroll
    for (int j = 0; j < 10; j++) {
      const float* wr = Wc + (k * 10 + j) * 32;  // wave-uniform -> s_load
      float xv = fv[j];
#pragma unroll
      for (int o = 0; o < 32; o++) acc[o] += xv * wr[o];
    }
  }
  float* xo = X + (size_t)g * NX + (size_t)n * 32;
#pragma unroll
  for (int o = 0; o < 32; o += 4) {
    float4 st = make_float4(fmaxf(acc[o], 0.f), fmaxf(acc[o + 1], 0.f),
                            fmaxf(acc[o + 2], 0.f), fmaxf(acc[o + 3], 0.f));
    *(float4*)(xo + o) = st;
  }
}

// ---------------- LSTM + factor update + next-iter prep ----------------
__global__ __launch_bounds__(256) void k_lstm(const float* __restrict__ X, float* __restrict__ H,
                                              float* __restrict__ C, float* __restrict__ Wws,
                                              float* __restrict__ feat, float* __restrict__ Z,
                                              const float* __restrict__ wts) {
  constexpr int NB = (NN + 255) / 256;
  int g = (blockIdx.x >= NB) ? 1 : 0;
  int n = (blockIdx.x - g * NB) * 256 + threadIdx.x;
  __shared__ float sigi[256 * 33];  // stride 33: bank-conflict-free per-thread slice
  if (n >= NN) return;
  const float* Wg = wts + (g ? WOFF_WGM : WOFF_WGU);
  const float* Ug = wts + (g ? WOFF_UGM : WOFF_UGU);
  const float* bg = wts + (g ? WOFF_BGM : WOFF_BGU);
  const float* Wo = wts + (g ? WOFF_WOH : WOFF_WOW);
  const float* bo = wts + (g ? WOFF_BOH : WOFF_BOW);
  const float* xp = X + (size_t)g * NX + (size_t)n * 32;
  float* hp = H + (size_t)g * NX + (size_t)n * 32;
  float* cp = C + (size_t)g * NX + (size_t)n * 32;
  float xr[32], hr[32], cr[32];
#pragma unroll
  for (int o = 0; o < 32; o += 4) {
    *(float4*)(xr + o) = *(const float4*)(xp + o);
    *(float4*)(hr + o) = *(const float4*)(hp + o);
    *(float4*)(cr + o) = *(const float4*)(cp + o);
  }
  float* si = &sigi[threadIdx.x * 33];
  // gate order: f(0) -> i(1, park in LDS) -> u(3) -> o(2); c fully updated before o epilogue
#pragma unroll 1
  for (int kk = 0; kk < 4; kk++) {
    int k = (kk == 0) ? 0 : (kk == 1) ? 1 : (kk == 2) ? 3 : 2;
    const float* wgk = Wg + k * 1024;
    const float* ugk = Ug + k * 1024;
    const float* bgk = bg + k * 32;
    float acc[32];
#pragma unroll
    for (int o = 0; o < 32; o++) acc[o] = bgk[o];
#pragma unroll
    for (int f = 0; f < 32; f++) {
      float xv = xr[f];
      const float* w = wgk + f * 32;  // wave-uniform -> s_load
#pragma unroll
      for (int o = 0; o < 32; o++) acc[o] += xv * w[o];
    }
#pragma unroll
    for (int f = 0; f < 32; f++) {
      float hv = hr[f];
      const float* w = ugk + f * 32;
#pragma unroll
      for (int o = 0; o < 32; o++) acc[o] += hv * w[o];
    }
#pragma unroll
    for (int o = 0; o < 32; o++) acc[o] = sigf(acc[o]);
    if (kk == 0) {
#pragma unroll
      for (int o = 0; o < 32; o++) cr[o] *= acc[o];
    } else if (kk == 1) {
#pragma unroll
      for (int o = 0; o < 32; o++) si[o] = acc[o];
    } else if (kk == 2) {
#pragma unroll
      for (int o = 0; o < 32; o++) cr[o] += si[o] * acc[o];
    } else {
#pragma unroll
      for (int o = 0; o < 32; o++) hr[o] = acc[o] * sigf(cr[o]);  // h = o * sigmoid(c) (faithful)
    }
  }
#pragma unroll
  for (int o = 0; o < 32; o += 4) {
    *(float4*)(hp + o) = *(float4*)(hr + o);
    *(float4*)(cp + o) = *(float4*)(cr + o);
  }
  // W += tanh(h_new @ W_out + b_out); also write feat T0 and Z(buf0) for next iteration
  float aw[10];
#pragma unroll
  for (int r = 0; r < 10; r++) aw[r] = bo[r];
#pragma unroll
  for (int f = 0; f < 32; f++) {
    float hv = hr[f];
    const float* w = Wo + f * 10;
#pragma unroll
    for (int r = 0; r < 10; r++) aw[r] += hv * w[r];
  }
  float* wrow = Wws + (size_t)g * NZ + (size_t)n * 12;
  float* frow = feat + (size_t)g * NF + (size_t)n * 60;
  float* zrow = Z + (size_t)g * 2 * NZ + (size_t)n * 12;
#pragma unroll
  for (int r = 0; r < 10; r++) {
    float t = fminf(fmaxf(aw[r], -15.f), 15.f);
    float e = __expf(2.f * t);
    float th = (e - 1.f) / (e + 1.f);
    float wn = wrow[r] + th;
    wrow[r] = wn;
    frow[r] = wn;
    zrow[r] = wn;
  }
}

// ---------------- final scoring ----------------
__global__ __launch_bounds__(256) void k_score(const int* __restrict__ uid, const int* __restrict__ iid,
                                               const float* __restrict__ Wws, void* __restrict__ outp,
                                               const int* __restrict__ flag) {
  int t = blockIdx.x * 256 + threadIdx.x;
  if (t >= 65536) return;
  int u = uid[t], i = iid[t];
  const float* wr = Wws + (size_t)u * 12;
  const float* hrp = Wws + NZ + (size_t)i * 12;
  float r = 0.f;
#pragma unroll
  for (int k = 0; k < 10; k++) r += wr[k] * hrp[k];
  float v = 1.f + 4.f * sigf(r);  // R_MIN + R_RANGE * sigmoid(r)
  if (flag[0]) ((u16*)outp)[t] = f2b(v);
  else         ((float*)outp)[t] = v;
}

// ---------------- host ----------------
extern "C" void kernel_launch(void* const* d_in, const int* in_sizes, int n_in,
                              void* d_out, int out_size, void* d_ws, size_t ws_size,
                              hipStream_t stream) {
  (void)in_sizes; (void)n_in; (void)out_size;
  if (ws_size < WS_NEED) return;  // fail loudly (validation will catch zeros)

  const int* uid = (const int*)d_in[0];
  const int* iid = (const int*)d_in[1];
  const int* ur = (const int*)d_in[2];
  const int* uc = (const int*)d_in[3];
  const void* uv = d_in[4];
  const int* ir = (const int*)d_in[5];
  const int* ic = (const int*)d_in[6];
  const void* iv = d_in[7];

  char* ws = (char*)d_ws;
  int* rowptr = (int*)(ws + OFF_ROWPTR);
  int* flag = rowptr + 2 * RP_ST - 1;  // spare slot past rp[NN] in graph-1 stride
  int* fill = (int*)(ws + OFF_FILL);
  int* count = (int*)(ws + OFF_COUNT);
  float* wts = (float*)(ws + OFF_COUNT);  // COUNT region is dead after k_scan; 82KB needed, 800KB available
  float* deg = (float*)(ws + OFF_DEG);
  float* dinv = (float*)(ws + OFF_DINV);
  float* Wws = (float*)(ws + OFF_W);
  float* Z = (float*)(ws + OFF_Z);
  float* feat = (float*)(ws + OFF_FEAT);
  float* X = (float*)(ws + OFF_X);
  float* H = (float*)(ws + OFF_H);
  float* C = (float*)(ws + OFF_C);
  int2* cedge = (int2*)(ws + OFF_CEDGE);

  // zero: count+deg (adjacent), h+c (adjacent)
  hipMemsetAsync(count, 0, 4 * (size_t)GSTRIDE * 4, stream);
  hipMemsetAsync(H, 0, 4 * NX * 4, stream);

  k_detect<<<1, 256, 0, stream>>>((const u16*)uv, flag);
  k_init<<<(2 * NN + 255) / 256, 256, 0, stream>>>(d_in[8], d_in[9], Wws, flag);
  k_hist<<<4096, 256, 0, stream>>>(ur, uv, ir, iv, count, deg, flag);
  k_scan<<<2, 1024, 0, stream>>>(count, rowptr, fill, deg, dinv);
  k_scatter<<<4096, 256, 0, stream>>>(ur, uc, uv, ir, ic, iv, dinv, fill, cedge, flag);
  P14 wp;
  for (int i = 0; i < 14; i++) wp.p[i] = d_in[10 + i];
  k_cvtw<<<(WTOTAL + 255) / 256, 256, 0, stream>>>(wp, wts, flag);  // after k_scan: count region dead
  k_prep<<<(2 * NN + 255) / 256, 256, 0, stream>>>(Wws, feat, Z);

  constexpr int CHEB_GRID = 2 * ((NN + 63) / 64);
  constexpr int NODE_GRID = 2 * ((NN + 255) / 256);
  for (int it = 0; it < 10; ++it) {
    k_cheb<1><<<CHEB_GRID, 256, 0, stream>>>(rowptr, cedge, feat, Z);
    k_cheb<2><<<CHEB_GRID, 256, 0, stream>>>(rowptr, cedge, feat, Z);
    k_cheb<3><<<CHEB_GRID, 256, 0, stream>>>(rowptr, cedge, feat, Z);
    k_cheb<4><<<CHEB_GRID, 256, 0, stream>>>(rowptr, cedge, feat, Z);
    k_conv<<<NODE_GRID, 256, 0, stream>>>(feat, X, wts);
    k_lstm<<<NODE_GRID, 256, 0, stream>>>(X, H, C, Wws, feat, Z, wts);
  }
  k_score<<<(65536 + 255) / 256, 256, 0, stream>>>(uid, iid, Wws, d_out, flag);
}

// Round 3
// 6746.411 us; speedup vs baseline: 1.1274x; 1.1274x over previous
//
#include <hip/hip_runtime.h>
#include <cstdint>

typedef unsigned short u16;
typedef unsigned int u32;
typedef unsigned long long u64;

#define NN 100000      // nodes per graph
#define EE 3200000     // edges per graph
constexpr int GS = 100032;  // padded per-graph stride

// ---------------- workspace layout (bytes) ----------------
constexpr size_t OFF_CNTDEG = 0;                                 // u64[2*GS] packed (count<<40 | deg fx26)
constexpr size_t OFF_DBIN   = OFF_CNTDEG + (size_t)2 * GS * 8;   // u32[512] dbin | u32[512] dfill | u32[512] doff | flag
constexpr size_t OFF_RPS    = OFF_DBIN + 8192;                   // int[2*GS] slot-order rowptr (NN+1 used)
constexpr size_t OFF_FILL   = OFF_RPS + (size_t)2 * GS * 4;
constexpr size_t OFF_PERM   = OFF_FILL + (size_t)2 * GS * 4;     // slot -> node
constexpr size_t OFF_ISLOT  = OFF_PERM + (size_t)2 * GS * 4;     // node -> slot
constexpr size_t OFF_DINV   = OFF_ISLOT + (size_t)2 * GS * 4;    // node order
constexpr int WTOTAL = 20564;
constexpr size_t OFF_WTS    = OFF_DINV + (size_t)2 * GS * 4;     // f32 packed weights
constexpr size_t OFF_W      = OFF_WTS + (size_t)WTOTAL * 4;      // f32[2*NN*12] factors, node order
constexpr size_t OFF_ZLO    = OFF_W + (size_t)2 * NN * 12 * 4;   // u32[2g*2buf*NN*4]: bf16 pairs r0..7
constexpr size_t OFF_ZHI    = OFF_ZLO + (size_t)2 * 2 * NN * 16; // u32[2g*2buf*NN]: bf16 pair r8,9
constexpr size_t OFF_FEAT   = OFF_ZHI + (size_t)2 * 2 * NN * 4;  // f32[2*NN*60] slot order (5 slices x 12)
constexpr size_t OFF_H      = OFF_FEAT + (size_t)2 * NN * 60 * 4;
constexpr size_t OFF_C      = OFF_H + (size_t)2 * NN * 32 * 4;
constexpr size_t OFF_CE     = OFF_C + (size_t)2 * NN * 32 * 4;   // u32[2*EE]: col<<15 | bf16(val)>>1bits
constexpr size_t WS_NEED    = OFF_CE + (size_t)2 * EE * 4;       // ~141 MB

// f32 weight pack offsets
constexpr int WOFF_WCW = 0, WOFF_BCW = 1600, WOFF_WCH = 1632, WOFF_BCH = 3232;
constexpr int WOFF_WGU = 3264, WOFF_UGU = 7360, WOFF_BGU = 11456;
constexpr int WOFF_WGM = 11584, WOFF_UGM = 15680, WOFF_BGM = 19776;
constexpr int WOFF_WOW = 19904, WOFF_BOW = 20224, WOFF_WOH = 20234, WOFF_BOH = 20554;

__device__ __forceinline__ float sigf(float x) { return 1.f / (1.f + __expf(-x)); }
__device__ __forceinline__ float ldf(const void* p, long long i, int bf) {
  if (bf) return __uint_as_float(((u32)((const u16*)p)[i]) << 16);
  return ((const float*)p)[i];
}
__device__ __forceinline__ u16 f2b(float f) {  // RNE f32->bf16
  u32 u = __float_as_uint(f);
  return (u16)((u + 0x7FFFu + ((u >> 16) & 1u)) >> 16);
}
__device__ __forceinline__ float b2f_lo(u32 u) { return __uint_as_float(u << 16); }
__device__ __forceinline__ float b2f_hi(u32 u) { return __uint_as_float(u & 0xFFFF0000u); }

// ---------------- dtype probe (bf16 vs f32 inputs) ----------------
__global__ __launch_bounds__(256) void k_detect(const u16* __restrict__ uv, u32* __restrict__ flag) {
  int t = threadIdx.x;
  u32 any = 0;
  for (int j = t; j < 8192; j += 256) any |= (uv[j] & 0x8000u);
  unsigned long long b = __ballot(any != 0);
  if (t == 0) flag[0] = (b == 0ull) ? 1u : 0u;  // uniform[0,1) positives: bf16 => bit15 never set
}

// ---------------- setup ----------------
__global__ __launch_bounds__(256) void k_init(const void* __restrict__ W0, const void* __restrict__ H0,
                                              float* __restrict__ W, const u32* __restrict__ flag) {
  int t = blockIdx.x * 256 + threadIdx.x;
  if (t >= 2 * NN) return;
  int bf = flag[0];
  int g = (t >= NN) ? 1 : 0;
  int n = t - g * NN;
  const void* src = g ? H0 : W0;
  float* dst = W + ((size_t)g * NN + n) * 12;
#pragma unroll
  for (int r = 0; r < 10; r++) dst[r] = ldf(src, (long long)n * 10 + r, bf);
  dst[10] = 0.f; dst[11] = 0.f;
}

// one u64 atomic per edge: (count 1)<<40 | fixed-point(val, 2^26)
__global__ __launch_bounds__(256) void k_hist(const int* __restrict__ ur, const void* __restrict__ uv,
                                              const int* __restrict__ ir, const void* __restrict__ iv,
                                              u64* __restrict__ cntdeg, const u32* __restrict__ flag) {
  int bf = flag[0];
  long long stride = (long long)gridDim.x * blockDim.x;
  for (long long t = (long long)blockIdx.x * blockDim.x + threadIdx.x; t < 2LL * EE; t += stride) {
    int g = (t >= EE) ? 1 : 0;
    int e = (int)(t - (long long)g * EE);
    int row = (g ? ir : ur)[e];
    float v = ldf(g ? iv : uv, e, bf);
    u64 pack = (1ull << 40) | (u64)(u32)(v * 67108864.f + 0.5f);
    atomicAdd(&cntdeg[(size_t)g * GS + row], pack);
  }
}

// degree histogram (256 buckets per graph)
__global__ __launch_bounds__(256) void k_dcount(const u64* __restrict__ cntdeg, u32* __restrict__ dbin) {
  __shared__ u32 lh[512];
  int tid = threadIdx.x;
  lh[tid] = 0; lh[tid + 256] = 0;
  __syncthreads();
  int t = blockIdx.x * 256 + tid;
  if (t < 2 * NN) {
    int g = (t >= NN) ? 1 : 0;
    int n = t - g * NN;
    u32 cnt = (u32)(cntdeg[(size_t)g * GS + n] >> 40);
    u32 d = cnt > 255u ? 255u : cnt;
    atomicAdd(&lh[g * 256 + d], 1u);
  }
  __syncthreads();
  if (lh[tid]) atomicAdd(&dbin[tid], lh[tid]);
  if (lh[tid + 256]) atomicAdd(&dbin[tid + 256], lh[tid + 256]);
}

// exclusive prefix over each graph's 256 buckets
__global__ __launch_bounds__(512) void k_dscan(const u32* __restrict__ dbin, u32* __restrict__ doff) {
  __shared__ u32 sh[512];
  int t = threadIdx.x;
  u32 own = dbin[t];
  sh[t] = own;
  __syncthreads();
  for (int off = 1; off < 256; off <<= 1) {
    u32 v = ((t & 255) >= off) ? sh[t - off] : 0;
    __syncthreads();
    sh[t] += v;
    __syncthreads();
  }
  doff[t] = sh[t] - own;
}

// place rows into degree-sorted slots; also compute dinv (node order)
__global__ __launch_bounds__(256) void k_dplace(const u64* __restrict__ cntdeg, const u32* __restrict__ doff,
                                                u32* __restrict__ dfill, int* __restrict__ perm,
                                                int* __restrict__ islot, float* __restrict__ dinv) {
  int t = blockIdx.x * 256 + threadIdx.x;
  if (t >= 2 * NN) return;
  int g = (t >= NN) ? 1 : 0;
  int n = t - g * NN;
  u64 u = cntdeg[(size_t)g * GS + n];
  u32 cnt = (u32)(u >> 40);
  u32 d = cnt > 255u ? 255u : cnt;
  u32 pos = doff[g * 256 + d] + atomicAdd(&dfill[g * 256 + d], 1u);
  perm[(size_t)g * GS + pos] = n;
  islot[(size_t)g * GS + n] = (int)pos;
  u64 dfx = u & 0xFFFFFFFFFFull;
  dinv[(size_t)g * GS + n] = dfx ? rsqrtf((float)dfx * (1.f / 67108864.f)) : 0.f;
}

// slot-order exclusive scan of permuted counts -> rowptr_s (+ fill copy)
__global__ __launch_bounds__(1024) void k_scan(const u64* __restrict__ cntdeg, const int* __restrict__ perm,
                                               int* __restrict__ rps, int* __restrict__ fill) {
  constexpr int CH = 98;
  int g = blockIdx.x, tid = threadIdx.x;
  const u64* cd = cntdeg + (size_t)g * GS;
  const int* pm = perm + (size_t)g * GS;
  int base = tid * CH;
  int s = 0;
  for (int j = 0; j < CH; j++) {
    int i = base + j;
    if (i < NN) s += (int)(cd[pm[i]] >> 40);
  }
  __shared__ int sh[1024];
  sh[tid] = s;
  __syncthreads();
  for (int off = 1; off < 1024; off <<= 1) {
    int v = (tid >= off) ? sh[tid - off] : 0;
    __syncthreads();
    sh[tid] += v;
    __syncthreads();
  }
  int run = sh[tid] - s;
  int* rp = rps + (size_t)g * GS;
  int* fl = fill + (size_t)g * GS;
  for (int j = 0; j < CH; j++) {
    int i = base + j;
    if (i >= NN) break;
    rp[i] = run; fl[i] = run;
    run += (int)(cd[pm[i]] >> 40);
  }
  if (tid == 1023) rp[NN] = run;  // == EE
}

// scatter edges into slot-ordered CSR; payload = col<<15 | bf16(val) (bit15 of positive bf16 is 0)
__global__ __launch_bounds__(256) void k_scatter(const int* __restrict__ ur, const int* __restrict__ uc,
                                                 const void* __restrict__ uv, const int* __restrict__ ir,
                                                 const int* __restrict__ ic, const void* __restrict__ iv,
                                                 const int* __restrict__ islot, int* __restrict__ fill,
                                                 u32* __restrict__ ce, const u32* __restrict__ flag) {
  int bf = flag[0];
  long long stride = (long long)gridDim.x * blockDim.x;
  for (long long t = (long long)blockIdx.x * blockDim.x + threadIdx.x; t < 2LL * EE; t += stride) {
    int g = (t >= EE) ? 1 : 0;
    int e = (int)(t - (long long)g * EE);
    int row = (g ? ir : ur)[e];
    int col = (g ? ic : uc)[e];
    float v = ldf(g ? iv : uv, e, bf);
    int sl = islot[(size_t)g * GS + row];
    int pos = atomicAdd(&fill[(size_t)g * GS + sl], 1);
    ce[(size_t)g * EE + pos] = ((u32)col << 15) | (u32)f2b(v);
  }
}

struct P14 { const void* p[14]; };
__global__ __launch_bounds__(256) void k_cvtw(P14 w, float* __restrict__ dst, const u32* __restrict__ flag) {
  int t = blockIdx.x * 256 + threadIdx.x;
  if (t >= WTOTAL) return;
  int bf = flag[0];
  const int sz[14] = {1600, 32, 1600, 32, 4096, 4096, 128, 4096, 4096, 128, 320, 10, 320, 10};
  int off = 0;
#pragma unroll
  for (int s = 0; s < 14; s++) {
    if (t < off + sz[s]) { dst[t] = ldf(w.p[s], t - off, bf); return; }
    off += sz[s];
  }
}

// T0 slice + Z buf0 = bf16(dinv*W)
__global__ __launch_bounds__(256) void k_prep(const float* __restrict__ W, const int* __restrict__ perm,
                                              const float* __restrict__ dinv, float* __restrict__ feat,
                                              u32* __restrict__ Zlo, u32* __restrict__ Zhi) {
  int t = blockIdx.x * 256 + threadIdx.x;
  if (t >= 2 * NN) return;
  int g = (t >= NN) ? 1 : 0;
  int slot = t - g * NN;
  int row = perm[(size_t)g * GS + slot];
  float dv = dinv[(size_t)g * GS + row];
  const float* w = W + ((size_t)g * NN + row) * 12;
  float* f = feat + ((size_t)g * NN + slot) * 60;
  float zv[10];
#pragma unroll
  for (int r = 0; r < 10; r++) { float x = w[r]; f[r] = x; zv[r] = dv * x; }
  size_t zo = ((size_t)g * 2 + 0) * NN + row;
  u32 p[5];
#pragma unroll
  for (int j = 0; j < 5; j++) p[j] = (u32)f2b(zv[2 * j]) | ((u32)f2b(zv[2 * j + 1]) << 16);
  *(uint4*)(Zlo + zo * 4) = make_uint4(p[0], p[1], p[2], p[3]);
  Zhi[zo] = p[4];
}

// ---------------- Chebyshev step (slot order, degree-balanced, XCD-swizzled) ----------------
// Z holds bf16(dinv ⊙ T_{K-1}); acc = Σ val * Z[col]; L(T)row = tprev - dinv_row * acc.
template <int K>
__global__ __launch_bounds__(256) void k_cheb(const int* __restrict__ rps, const u32* __restrict__ ce,
                                              const int* __restrict__ perm, const float* __restrict__ dinv,
                                              float* __restrict__ feat, u32* __restrict__ Zlo,
                                              u32* __restrict__ Zhi) {
  constexpr int NBG = (NN + 63) / 64;  // 1563 slot-blocks per graph
  int x = blockIdx.x;
  int xcd = x & 7;                      // blockIdx%8 ~ XCD (heuristic; perf only)
  int g = xcd >> 2;                     // graph 0 -> XCDs 0-3, graph 1 -> 4-7 (Z stays L2-local)
  int b = (x >> 3) * 4 + (xcd & 3);
  if (b >= NBG) return;
  int tid = threadIdx.x;
  int l = tid & 3;
  int slot = b * 64 + (tid >> 2);
  const u32* ZloIn = Zlo + (((size_t)g * 2 + ((K - 1) & 1)) * NN) * 4;
  const u32* ZhiIn = Zhi + ((size_t)g * 2 + ((K - 1) & 1)) * NN;
  float acc[10];
#pragma unroll
  for (int r = 0; r < 10; r++) acc[r] = 0.f;
  if (slot < NN) {
    const int* rp = rps + (size_t)g * GS;
    int e1 = rp[slot + 1];
    const u32* cep = ce + (size_t)g * EE;
    for (int e = rp[slot] + l; e < e1; e += 4) {
      u32 ec = cep[e];
      float c = __uint_as_float((ec & 0x7FFFu) << 16);
      u32 col = ec >> 15;
      uint4 q = *(const uint4*)(ZloIn + (size_t)col * 4);
      u32 h = ZhiIn[col];
      acc[0] += c * b2f_lo(q.x); acc[1] += c * b2f_hi(q.x);
      acc[2] += c * b2f_lo(q.y); acc[3] += c * b2f_hi(q.y);
      acc[4] += c * b2f_lo(q.z); acc[5] += c * b2f_hi(q.z);
      acc[6] += c * b2f_lo(q.w); acc[7] += c * b2f_hi(q.w);
      acc[8] += c * b2f_lo(h);   acc[9] += c * b2f_hi(h);
    }
  }
#pragma unroll
  for (int r = 0; r < 10; r++) {
    acc[r] += __shfl_xor(acc[r], 1);
    acc[r] += __shfl_xor(acc[r], 2);
  }
  if (l == 0 && slot < NN) {
    int row = perm[(size_t)g * GS + slot];
    float dv = dinv[(size_t)g * GS + row];
    float* frow = feat + ((size_t)g * NN + slot) * 60;
    float tv[10];
#pragma unroll
    for (int r = 0; r < 10; r++) {
      float tprev = frow[(K - 1) * 12 + r];
      float t = tprev - dv * acc[r];  // L(T_{K-1})
      if constexpr (K >= 2) t = 2.f * t - frow[(K - 2) * 12 + r];
      frow[K * 12 + r] = t;
      tv[r] = dv * t;
    }
    if constexpr (K < 4) {  // K=4's Z never consumed
      size_t zo = ((size_t)g * 2 + (K & 1)) * NN + row;
      u32 p[5];
#pragma unroll
      for (int j = 0; j < 5; j++) p[j] = (u32)f2b(tv[2 * j]) | ((u32)f2b(tv[2 * j + 1]) << 16);
      *(uint4*)(Zlo + zo * 4) = make_uint4(p[0], p[1], p[2], p[3]);
      Zhi[zo] = p[4];
    }
  }
}

// ---------------- fused conv + LSTM + factor update + next-iter prep ----------------
__global__ __launch_bounds__(256) void k_convlstm(const float* __restrict__ feat_c, float* __restrict__ H,
                                                  float* __restrict__ C, float* __restrict__ W,
                                                  const int* __restrict__ perm, const float* __restrict__ dinv,
                                                  float* __restrict__ feat, u32* __restrict__ Zlo,
                                                  u32* __restrict__ Zhi, const float* __restrict__ wts) {
  constexpr int NB = (NN + 255) / 256;  // 391
  int g = (blockIdx.x >= NB) ? 1 : 0;
  int n = (blockIdx.x - g * NB) * 256 + threadIdx.x;
  __shared__ float sigi[256 * 33];
  if (n >= NN) return;
  const float* Wc = wts + (g ? WOFF_WCH : WOFF_WCW);
  const float* bc = wts + (g ? WOFF_BCH : WOFF_BCW);
  const float* Wg = wts + (g ? WOFF_WGM : WOFF_WGU);
  const float* Ug = wts + (g ? WOFF_UGM : WOFF_UGU);
  const float* bg = wts + (g ? WOFF_BGM : WOFF_BGU);
  const float* Wo = wts + (g ? WOFF_WOH : WOFF_WOW);
  const float* bo = wts + (g ? WOFF_BOH : WOFF_BOW);
  // conv: xr = relu(feat[50] @ Wc + bc)
  const float* frow_c = feat_c + ((size_t)g * NN + n) * 60;
  float xr[32];
#pragma unroll
  for (int o = 0; o < 32; o++) xr[o] = bc[o];
#pragma unroll
  for (int k = 0; k < 5; k++) {
    const float4* f4 = (const float4*)(frow_c + k * 12);
    float4 a = f4[0], b2 = f4[1], c2 = f4[2];
    float fv[10] = {a.x, a.y, a.z, a.w, b2.x, b2.y, b2.z, b2.w, c2.x, c2.y};
#pragma unroll
    for (int j = 0; j < 10; j++) {
      const float* wr = Wc + (k * 10 + j) * 32;  // wave-uniform -> s_load
      float xv = fv[j];
#pragma unroll
      for (int o = 0; o < 32; o++) xr[o] += xv * wr[o];
    }
  }
#pragma unroll
  for (int o = 0; o < 32; o++) xr[o] = fmaxf(xr[o], 0.f);
  // lstm
  float* hp = H + ((size_t)g * NN + n) * 32;
  float* cp = C + ((size_t)g * NN + n) * 32;
  float hr[32], cr[32];
#pragma unroll
  for (int o = 0; o < 32; o += 4) {
    *(float4*)(hr + o) = *(const float4*)(hp + o);
    *(float4*)(cr + o) = *(const float4*)(cp + o);
  }
  float* si = &sigi[threadIdx.x * 33];
#pragma unroll 1
  for (int kk = 0; kk < 4; kk++) {  // f, i(->LDS), u, o
    int k = (kk == 0) ? 0 : (kk == 1) ? 1 : (kk == 2) ? 3 : 2;
    const float* wgk = Wg + k * 1024;
    const float* ugk = Ug + k * 1024;
    const float* bgk = bg + k * 32;
    float acc[32];
#pragma unroll
    for (int o = 0; o < 32; o++) acc[o] = bgk[o];
#pragma unroll
    for (int f = 0; f < 32; f++) {
      float xv = xr[f];
      const float* w = wgk + f * 32;
#pragma unroll
      for (int o = 0; o < 32; o++) acc[o] += xv * w[o];
    }
#pragma unroll
    for (int f = 0; f < 32; f++) {
      float hv = hr[f];
      const float* w = ugk + f * 32;
#pragma unroll
      for (int o = 0; o < 32; o++) acc[o] += hv * w[o];
    }
#pragma unroll
    for (int o = 0; o < 32; o++) acc[o] = sigf(acc[o]);
    if (kk == 0) {
#pragma unroll
      for (int o = 0; o < 32; o++) cr[o] *= acc[o];
    } else if (kk == 1) {
#pragma unroll
      for (int o = 0; o < 32; o++) si[o] = acc[o];
    } else if (kk == 2) {
#pragma unroll
      for (int o = 0; o < 32; o++) cr[o] += si[o] * acc[o];
    } else {
#pragma unroll
      for (int o = 0; o < 32; o++) hr[o] = acc[o] * sigf(cr[o]);  // h = o*sigmoid(c) (faithful)
    }
  }
#pragma unroll
  for (int o = 0; o < 32; o += 4) {
    *(float4*)(hp + o) = *(float4*)(hr + o);
    *(float4*)(cp + o) = *(float4*)(cr + o);
  }
  // W += tanh(h @ W_out + b_out); refresh feat slice0 + Z buf0
  float aw[10];
#pragma unroll
  for (int r = 0; r < 10; r++) aw[r] = bo[r];
#pragma unroll
  for (int f = 0; f < 32; f++) {
    float hv = hr[f];
    const float* w = Wo + f * 10;
#pragma unroll
    for (int r = 0; r < 10; r++) aw[r] += hv * w[r];
  }
  int row = perm[(size_t)g * GS + n];
  float dv = dinv[(size_t)g * GS + row];
  float* wrow = W + ((size_t)g * NN + row) * 12;
  float* frow = feat + ((size_t)g * NN + n) * 60;
  float zv[10];
#pragma unroll
  for (int r = 0; r < 10; r++) {
    float t = fminf(fmaxf(aw[r], -15.f), 15.f);
    float e = __expf(2.f * t);
    float th = (e - 1.f) / (e + 1.f);
    float wn = wrow[r] + th;
    wrow[r] = wn;
    frow[r] = wn;
    zv[r] = dv * wn;
  }
  size_t zo = ((size_t)g * 2 + 0) * NN + row;
  u32 p[5];
#pragma unroll
  for (int j = 0; j < 5; j++) p[j] = (u32)f2b(zv[2 * j]) | ((u32)f2b(zv[2 * j + 1]) << 16);
  *(uint4*)(Zlo + zo * 4) = make_uint4(p[0], p[1], p[2], p[3]);
  Zhi[zo] = p[4];
}

// ---------------- scoring ----------------
__global__ __launch_bounds__(256) void k_score(const int* __restrict__ uid, const int* __restrict__ iid,
                                               const float* __restrict__ W, void* __restrict__ outp,
                                               const u32* __restrict__ flag) {
  int t = blockIdx.x * 256 + threadIdx.x;
  if (t >= 65536) return;
  int u = uid[t], i = iid[t];
  const float* wr = W + (size_t)u * 12;
  const float* hr = W + ((size_t)NN + i) * 12;
  float r = 0.f;
#pragma unroll
  for (int k = 0; k < 10; k++) r += wr[k] * hr[k];
  float v = 1.f + 4.f * sigf(r);
  if (flag[0]) ((u16*)outp)[t] = f2b(v);
  else         ((float*)outp)[t] = v;
}

// ---------------- host ----------------
extern "C" void kernel_launch(void* const* d_in, const int* in_sizes, int n_in,
                              void* d_out, int out_size, void* d_ws, size_t ws_size,
                              hipStream_t stream) {
  (void)in_sizes; (void)n_in; (void)out_size;
  if (ws_size < WS_NEED) return;

  const int* uid = (const int*)d_in[0];
  const int* iid = (const int*)d_in[1];
  const int* ur = (const int*)d_in[2];
  const int* uc = (const int*)d_in[3];
  const void* uv = d_in[4];
  const int* ir = (const int*)d_in[5];
  const int* ic = (const int*)d_in[6];
  const void* iv = d_in[7];

  char* ws = (char*)d_ws;
  u64* cntdeg = (u64*)(ws + OFF_CNTDEG);
  u32* dbin = (u32*)(ws + OFF_DBIN);
  u32* dfill = dbin + 512;
  u32* doff = dbin + 1024;
  u32* flag = dbin + 1536;
  int* rps = (int*)(ws + OFF_RPS);
  int* fill = (int*)(ws + OFF_FILL);
  int* perm = (int*)(ws + OFF_PERM);
  int* islot = (int*)(ws + OFF_ISLOT);
  float* dinv = (float*)(ws + OFF_DINV);
  float* wts = (float*)(ws + OFF_WTS);
  float* W = (float*)(ws + OFF_W);
  u32* Zlo = (u32*)(ws + OFF_ZLO);
  u32* Zhi = (u32*)(ws + OFF_ZHI);
  float* feat = (float*)(ws + OFF_FEAT);
  float* H = (float*)(ws + OFF_H);
  float* C = (float*)(ws + OFF_C);
  u32* ce = (u32*)(ws + OFF_CE);

  // zero cntdeg + dbin + dfill (contiguous), and H+C (contiguous)
  hipMemsetAsync(ws, 0, OFF_DBIN + 4096, stream);
  hipMemsetAsync(ws + OFF_H, 0, (size_t)4 * NN * 32 * 4, stream);

  k_detect<<<1, 256, 0, stream>>>((const u16*)uv, flag);
  k_init<<<(2 * NN + 255) / 256, 256, 0, stream>>>(d_in[8], d_in[9], W, flag);
  k_hist<<<4096, 256, 0, stream>>>(ur, uv, ir, iv, cntdeg, flag);
  k_dcount<<<(2 * NN + 255) / 256, 256, 0, stream>>>(cntdeg, dbin);
  k_dscan<<<1, 512, 0, stream>>>(dbin, doff);
  k_dplace<<<(2 * NN + 255) / 256, 256, 0, stream>>>(cntdeg, doff, dfill, perm, islot, dinv);
  k_scan<<<2, 1024, 0, stream>>>(cntdeg, perm, rps, fill);
  k_scatter<<<4096, 256, 0, stream>>>(ur, uc, uv, ir, ic, iv, islot, fill, ce, flag);
  P14 wp;
  for (int i = 0; i < 14; i++) wp.p[i] = d_in[10 + i];
  k_cvtw<<<(WTOTAL + 255) / 256, 256, 0, stream>>>(wp, wts, flag);
  k_prep<<<(2 * NN + 255) / 256, 256, 0, stream>>>(W, perm, dinv, feat, Zlo, Zhi);

  constexpr int NBG = (NN + 63) / 64;           // 1563
  constexpr int CHEB_GRID = 8 * ((NBG + 3) / 4);  // 3128, XCD-swizzled
  constexpr int NODE_GRID = 2 * ((NN + 255) / 256);
  for (int it = 0; it < 10; ++it) {
    k_cheb<1><<<CHEB_GRID, 256, 0, stream>>>(rps, ce, perm, dinv, feat, Zlo, Zhi);
    k_cheb<2><<<CHEB_GRID, 256, 0, stream>>>(rps, ce, perm, dinv, feat, Zlo, Zhi);
    k_cheb<3><<<CHEB_GRID, 256, 0, stream>>>(rps, ce, perm, dinv, feat, Zlo, Zhi);
    k_cheb<4><<<CHEB_GRID, 256, 0, stream>>>(rps, ce, perm, dinv, feat, Zlo, Zhi);
    k_convlstm<<<NODE_GRID, 256, 0, stream>>>(feat, H, C, W, perm, dinv, feat, Zlo, Zhi, wts);
  }
  k_score<<<256, 256, 0, stream>>>(uid, iid, W, d_out, flag);
}

// Round 4
// 6162.357 us; speedup vs baseline: 1.2342x; 1.0948x over previous
//
#include <hip/hip_runtime.h>
#include <hip/hip_fp16.h>
#include <cstdint>

typedef unsigned short u16;
typedef unsigned int u32;
typedef unsigned long long u64;

#define NN 100000      // nodes per graph
#define EE 3200000     // edges per graph
constexpr int GS = 100032;  // padded per-graph stride

// ---------------- workspace layout (bytes) ----------------
constexpr size_t OFF_CNTDEG = 0;                                 // u64[2*GS] packed (count<<40 | deg fx26)
constexpr size_t OFF_DBIN   = OFF_CNTDEG + (size_t)2 * GS * 8;   // dbin[512]|dfill[512]|doff[512]|bsum[1024]|flag
constexpr size_t OFF_RPS    = OFF_DBIN + 12288;                  // int[2*GS] slot-order rowptr (NN+1 used)
constexpr size_t OFF_FILL   = OFF_RPS + (size_t)2 * GS * 4;
constexpr size_t OFF_PERM   = OFF_FILL + (size_t)2 * GS * 4;     // slot -> node
constexpr size_t OFF_ISLOT  = OFF_PERM + (size_t)2 * GS * 4;     // node -> slot
constexpr size_t OFF_DINV   = OFF_ISLOT + (size_t)2 * GS * 4;    // node order
constexpr int WTOTAL = 20564;
constexpr size_t OFF_WTS    = OFF_DINV + (size_t)2 * GS * 4;     // f32 packed weights
constexpr size_t OFF_W      = OFF_WTS + (size_t)WTOTAL * 4;      // f32[2*NN*12] factors, node order
constexpr size_t OFF_ZLO    = OFF_W + (size_t)2 * NN * 12 * 4;   // u32[2g*2buf*NN*4]: fp16 pairs r0..7
constexpr size_t OFF_ZHI    = OFF_ZLO + (size_t)2 * 2 * NN * 16; // u32[2g*2buf*NN]: fp16 pair r8,9
constexpr size_t OFF_FEAT   = OFF_ZHI + (size_t)2 * 2 * NN * 4;  // f32[2*NN*60] slot order (5 slices x 12)
constexpr size_t OFF_H      = OFF_FEAT + (size_t)2 * NN * 60 * 4;
constexpr size_t OFF_C      = OFF_H + (size_t)2 * NN * 32 * 4;
constexpr size_t OFF_CE     = OFF_C + (size_t)2 * NN * 32 * 4;   // u32[2*EE]: col<<15 | fp16(val) (bit15==0)
constexpr size_t WS_NEED    = OFF_CE + (size_t)2 * EE * 4;       // ~141 MB

// f32 weight pack offsets
constexpr int WOFF_WCW = 0, WOFF_BCW = 1600, WOFF_WCH = 1632, WOFF_BCH = 3232;
constexpr int WOFF_WGU = 3264, WOFF_UGU = 7360, WOFF_BGU = 11456;
constexpr int WOFF_WGM = 11584, WOFF_UGM = 15680, WOFF_BGM = 19776;
constexpr int WOFF_WOW = 19904, WOFF_BOW = 20224, WOFF_WOH = 20234, WOFF_BOH = 20554;

constexpr int NBPG = (NN + 255) / 256;  // 391 node-blocks per graph

__device__ __forceinline__ float sigf(float x) { return 1.f / (1.f + __expf(-x)); }
__device__ __forceinline__ float ldf(const void* p, long long i, int bf) {
  if (bf) return __uint_as_float(((u32)((const u16*)p)[i]) << 16);
  return ((const float*)p)[i];
}
__device__ __forceinline__ u16 f2b(float f) {  // RNE f32->bf16 (output only)
  u32 u = __float_as_uint(f);
  return (u16)((u + 0x7FFFu + ((u >> 16) & 1u)) >> 16);
}
// fp16 helpers: fma_mix-friendly (acc += c * h_half fuses to v_fma_mix_f32)
__device__ __forceinline__ float h_lo(u32 u) { return __half2float(__ushort_as_half((u16)u)); }
__device__ __forceinline__ float h_hi(u32 u) { return __half2float(__ushort_as_half((u16)(u >> 16))); }
__device__ __forceinline__ float h_15(u32 u) { return __half2float(__ushort_as_half((u16)(u & 0x7FFFu))); }
__device__ __forceinline__ u32 pk_h2(float a, float b) {
  return (u32)__half_as_ushort(__float2half(a)) | ((u32)__half_as_ushort(__float2half(b)) << 16);
}

// ---------------- dtype probe (bf16 vs f32 inputs) ----------------
__global__ __launch_bounds__(256) void k_detect(const u16* __restrict__ uv, u32* __restrict__ flag) {
  int t = threadIdx.x;
  u32 any = 0;
  for (int j = t; j < 8192; j += 256) any |= (uv[j] & 0x8000u);
  unsigned long long b = __ballot(any != 0);
  if (t == 0) flag[0] = (b == 0ull) ? 1u : 0u;  // uniform[0,1) positives: bf16 => bit15 never set
}

// ---------------- setup ----------------
__global__ __launch_bounds__(256) void k_init(const void* __restrict__ W0, const void* __restrict__ H0,
                                              float* __restrict__ W, const u32* __restrict__ flag) {
  int t = blockIdx.x * 256 + threadIdx.x;
  if (t >= 2 * NN) return;
  int bf = flag[0];
  int g = (t >= NN) ? 1 : 0;
  int n = t - g * NN;
  const void* src = g ? H0 : W0;
  float* dst = W + ((size_t)g * NN + n) * 12;
#pragma unroll
  for (int r = 0; r < 10; r++) dst[r] = ldf(src, (long long)n * 10 + r, bf);
  dst[10] = 0.f; dst[11] = 0.f;
}

// one u64 atomic per edge: (count 1)<<40 | fixed-point(val, 2^26)
__global__ __launch_bounds__(256) void k_hist(const int* __restrict__ ur, const void* __restrict__ uv,
                                              const int* __restrict__ ir, const void* __restrict__ iv,
                                              u64* __restrict__ cntdeg, const u32* __restrict__ flag) {
  int bf = flag[0];
  long long stride = (long long)gridDim.x * blockDim.x;
  for (long long t = (long long)blockIdx.x * blockDim.x + threadIdx.x; t < 2LL * EE; t += stride) {
    int g = (t >= EE) ? 1 : 0;
    int e = (int)(t - (long long)g * EE);
    int row = (g ? ir : ur)[e];
    float v = ldf(g ? iv : uv, e, bf);
    u64 pack = (1ull << 40) | (u64)(u32)(v * 67108864.f + 0.5f);
    atomicAdd(&cntdeg[(size_t)g * GS + row], pack);
  }
}

// degree histogram (256 buckets per graph)
__global__ __launch_bounds__(256) void k_dcount(const u64* __restrict__ cntdeg, u32* __restrict__ dbin) {
  __shared__ u32 lh[512];
  int tid = threadIdx.x;
  lh[tid] = 0; lh[tid + 256] = 0;
  __syncthreads();
  int t = blockIdx.x * 256 + tid;
  if (t < 2 * NN) {
    int g = (t >= NN) ? 1 : 0;
    int n = t - g * NN;
    u32 cnt = (u32)(cntdeg[(size_t)g * GS + n] >> 40);
    u32 d = cnt > 255u ? 255u : cnt;
    atomicAdd(&lh[g * 256 + d], 1u);
  }
  __syncthreads();
  if (lh[tid]) atomicAdd(&dbin[tid], lh[tid]);
  if (lh[tid + 256]) atomicAdd(&dbin[tid + 256], lh[tid + 256]);
}

// exclusive prefix over each graph's 256 buckets
__global__ __launch_bounds__(512) void k_dscan(const u32* __restrict__ dbin, u32* __restrict__ doff) {
  __shared__ u32 sh[512];
  int t = threadIdx.x;
  u32 own = dbin[t];
  sh[t] = own;
  __syncthreads();
  for (int off = 1; off < 256; off <<= 1) {
    u32 v = ((t & 255) >= off) ? sh[t - off] : 0;
    __syncthreads();
    sh[t] += v;
    __syncthreads();
  }
  doff[t] = sh[t] - own;
}

// place rows into degree-sorted slots; also compute dinv (node order)
__global__ __launch_bounds__(256) void k_dplace(const u64* __restrict__ cntdeg, const u32* __restrict__ doff,
                                                u32* __restrict__ dfill, int* __restrict__ perm,
                                                int* __restrict__ islot, float* __restrict__ dinv) {
  int t = blockIdx.x * 256 + threadIdx.x;
  if (t >= 2 * NN) return;
  int g = (t >= NN) ? 1 : 0;
  int n = t - g * NN;
  u64 u = cntdeg[(size_t)g * GS + n];
  u32 cnt = (u32)(u >> 40);
  u32 d = cnt > 255u ? 255u : cnt;
  u32 pos = doff[g * 256 + d] + atomicAdd(&dfill[g * 256 + d], 1u);
  perm[(size_t)g * GS + pos] = n;
  islot[(size_t)g * GS + n] = (int)pos;
  u64 dfx = u & 0xFFFFFFFFFFull;
  dinv[(size_t)g * GS + n] = dfx ? rsqrtf((float)dfx * (1.f / 67108864.f)) : 0.f;
}

// ---------------- parallel 3-phase scan over permuted counts ----------------
// phase 1: per-256-block LDS scan; local-exclusive into rps, block total into bsum
__global__ __launch_bounds__(256) void k_scan1(const u64* __restrict__ cntdeg, const int* __restrict__ perm,
                                               int* __restrict__ rps, int* __restrict__ bsum) {
  int g = (blockIdx.x >= NBPG) ? 1 : 0;
  int b = blockIdx.x - g * NBPG;
  int tid = threadIdx.x;
  int i = b * 256 + tid;
  int c = 0;
  if (i < NN) c = (int)(cntdeg[(size_t)g * GS + perm[(size_t)g * GS + i]] >> 40);
  __shared__ int sh[256];
  sh[tid] = c;
  __syncthreads();
  for (int off = 1; off < 256; off <<= 1) {
    int v = (tid >= off) ? sh[tid - off] : 0;
    __syncthreads();
    sh[tid] += v;
    __syncthreads();
  }
  int incl = sh[tid];
  if (i < NN) rps[(size_t)g * GS + i] = incl - c;
  if (tid == 255) bsum[g * 512 + b] = incl;
}

// phase 2: scan each graph's 391 block sums -> exclusive block offsets (in place)
__global__ __launch_bounds__(512) void k_scan2(int* __restrict__ bsum) {
  int g = blockIdx.x;
  int t = threadIdx.x;
  __shared__ int sh[512];
  int v = (t < NBPG) ? bsum[g * 512 + t] : 0;
  int own = v;
  sh[t] = v;
  __syncthreads();
  for (int off = 1; off < 512; off <<= 1) {
    int u2 = (t >= off) ? sh[t - off] : 0;
    __syncthreads();
    sh[t] += u2;
    __syncthreads();
  }
  if (t < NBPG) bsum[g * 512 + t] = sh[t] - own;
}

// phase 3: add block offsets; write fill copy and rp[NN]
__global__ __launch_bounds__(256) void k_scan3(int* __restrict__ rps, int* __restrict__ fill,
                                               const int* __restrict__ bsum) {
  int g = (blockIdx.x >= NBPG) ? 1 : 0;
  int b = blockIdx.x - g * NBPG;
  int i = b * 256 + threadIdx.x;
  if (i < NN) {
    int v = rps[(size_t)g * GS + i] + bsum[g * 512 + b];
    rps[(size_t)g * GS + i] = v;
    fill[(size_t)g * GS + i] = v;
  }
  if (b == 0 && threadIdx.x == 0) rps[(size_t)g * GS + NN] = EE;
}

// scatter edges into slot-ordered CSR; payload = col<<15 | fp16(val) (val<=1 => fits 15 bits)
__global__ __launch_bounds__(256) void k_scatter(const int* __restrict__ ur, const int* __restrict__ uc,
                                                 const void* __restrict__ uv, const int* __restrict__ ir,
                                                 const int* __restrict__ ic, const void* __restrict__ iv,
                                                 const int* __restrict__ islot, int* __restrict__ fill,
                                                 u32* __restrict__ ce, const u32* __restrict__ flag) {
  int bf = flag[0];
  long long stride = (long long)gridDim.x * blockDim.x;
  for (long long t = (long long)blockIdx.x * blockDim.x + threadIdx.x; t < 2LL * EE; t += stride) {
    int g = (t >= EE) ? 1 : 0;
    int e = (int)(t - (long long)g * EE);
    int row = (g ? ir : ur)[e];
    int col = (g ? ic : uc)[e];
    float v = ldf(g ? iv : uv, e, bf);
    int sl = islot[(size_t)g * GS + row];
    int pos = atomicAdd(&fill[(size_t)g * GS + sl], 1);
    ce[(size_t)g * EE + pos] = ((u32)col << 15) | (u32)__half_as_ushort(__float2half(v));
  }
}

struct P14 { const void* p[14]; };
__global__ __launch_bounds__(256) void k_cvtw(P14 w, float* __restrict__ dst, const u32* __restrict__ flag) {
  int t = blockIdx.x * 256 + threadIdx.x;
  if (t >= WTOTAL) return;
  int bf = flag[0];
  const int sz[14] = {1600, 32, 1600, 32, 4096, 4096, 128, 4096, 4096, 128, 320, 10, 320, 10};
  int off = 0;
#pragma unroll
  for (int s = 0; s < 14; s++) {
    if (t < off + sz[s]) { dst[t] = ldf(w.p[s], t - off, bf); return; }
    off += sz[s];
  }
}

// T0 slice + Z buf0 = fp16(dinv*W)
__global__ __launch_bounds__(256) void k_prep(const float* __restrict__ W, const int* __restrict__ perm,
                                              const float* __restrict__ dinv, float* __restrict__ feat,
                                              u32* __restrict__ Zlo, u32* __restrict__ Zhi) {
  int t = blockIdx.x * 256 + threadIdx.x;
  if (t >= 2 * NN) return;
  int g = (t >= NN) ? 1 : 0;
  int slot = t - g * NN;
  int row = perm[(size_t)g * GS + slot];
  float dv = dinv[(size_t)g * GS + row];
  const float* w = W + ((size_t)g * NN + row) * 12;
  float* f = feat + ((size_t)g * NN + slot) * 60;
  float zv[10];
#pragma unroll
  for (int r = 0; r < 10; r++) { float x = w[r]; f[r] = x; zv[r] = dv * x; }
  size_t zo = ((size_t)g * 2 + 0) * NN + row;
  *(uint4*)(Zlo + zo * 4) = make_uint4(pk_h2(zv[0], zv[1]), pk_h2(zv[2], zv[3]),
                                       pk_h2(zv[4], zv[5]), pk_h2(zv[6], zv[7]));
  Zhi[zo] = pk_h2(zv[8], zv[9]);
}

// ---------------- Chebyshev step (slot order, degree-balanced, XCD-swizzled) ----------------
// Z holds fp16(dinv ⊙ T_{K-1}); acc = Σ val * Z[col]; L(T)row = tprev - dinv_row * acc.
// Uniform predicated inner loop (pad edges decode to c=0 => exact no-op), unrolled x2 for MLP.
template <int K>
__global__ __launch_bounds__(256) void k_cheb(const int* __restrict__ rps, const u32* __restrict__ ce,
                                              const int* __restrict__ perm, const float* __restrict__ dinv,
                                              float* __restrict__ feat, u32* __restrict__ Zlo,
                                              u32* __restrict__ Zhi) {
  constexpr int NBG = (NN + 63) / 64;  // 1563 slot-blocks per graph
  int x = blockIdx.x;
  int xcd = x & 7;                      // blockIdx%8 ~ XCD (perf heuristic only)
  int g = xcd >> 2;                     // graph 0 -> XCDs 0-3, graph 1 -> 4-7
  int b = (x >> 3) * 4 + (xcd & 3);
  if (b >= NBG) return;
  int tid = threadIdx.x;
  int l = tid & 3;
  int slot = b * 64 + (tid >> 2);
  const u32* ZloIn = Zlo + (((size_t)g * 2 + ((K - 1) & 1)) * NN) * 4;
  const u32* ZhiIn = Zhi + ((size_t)g * 2 + ((K - 1) & 1)) * NN;
  float acc[10];
#pragma unroll
  for (int r = 0; r < 10; r++) acc[r] = 0.f;
  bool rowok = slot < NN;
  int e0 = 0, e1 = 0;
  if (rowok) {
    const int* rp = rps + (size_t)g * GS;
    e0 = rp[slot];
    e1 = rp[slot + 1];
  }
  const u32* cep = ce + (size_t)g * EE;
  int nit = rowok ? ((e1 - e0 + 3) >> 2) : 0;
  int e = e0 + l;
  for (int it = 0; it < nit; it += 2, e += 8) {
    u32 eca = (e < e1) ? cep[e] : 0u;
    u32 ecb = (e + 4 < e1) ? cep[e + 4] : 0u;
    u32 cola = eca >> 15, colb = ecb >> 15;
    float ca = h_15(eca), cb = h_15(ecb);
    uint4 qa = *(const uint4*)(ZloIn + (size_t)cola * 4);
    u32 ha = ZhiIn[cola];
    uint4 qb = *(const uint4*)(ZloIn + (size_t)colb * 4);
    u32 hb = ZhiIn[colb];
    acc[0] += ca * h_lo(qa.x); acc[1] += ca * h_hi(qa.x);
    acc[2] += ca * h_lo(qa.y); acc[3] += ca * h_hi(qa.y);
    acc[4] += ca * h_lo(qa.z); acc[5] += ca * h_hi(qa.z);
    acc[6] += ca * h_lo(qa.w); acc[7] += ca * h_hi(qa.w);
    acc[8] += ca * h_lo(ha);   acc[9] += ca * h_hi(ha);
    acc[0] += cb * h_lo(qb.x); acc[1] += cb * h_hi(qb.x);
    acc[2] += cb * h_lo(qb.y); acc[3] += cb * h_hi(qb.y);
    acc[4] += cb * h_lo(qb.z); acc[5] += cb * h_hi(qb.z);
    acc[6] += cb * h_lo(qb.w); acc[7] += cb * h_hi(qb.w);
    acc[8] += cb * h_lo(hb);   acc[9] += cb * h_hi(hb);
  }
#pragma unroll
  for (int r = 0; r < 10; r++) {
    acc[r] += __shfl_xor(acc[r], 1);
    acc[r] += __shfl_xor(acc[r], 2);
  }
  if (l == 0 && rowok) {
    int row = perm[(size_t)g * GS + slot];
    float dv = dinv[(size_t)g * GS + row];
    float* frow = feat + ((size_t)g * NN + slot) * 60;
    float tv[10];
#pragma unroll
    for (int r = 0; r < 10; r++) {
      float tprev = frow[(K - 1) * 12 + r];
      float t = tprev - dv * acc[r];  // L(T_{K-1})
      if constexpr (K >= 2) t = 2.f * t - frow[(K - 2) * 12 + r];
      frow[K * 12 + r] = t;
      tv[r] = dv * t;
    }
    if constexpr (K < 4) {  // K=4's Z never consumed
      size_t zo = ((size_t)g * 2 + (K & 1)) * NN + row;
      *(uint4*)(Zlo + zo * 4) = make_uint4(pk_h2(tv[0], tv[1]), pk_h2(tv[2], tv[3]),
                                           pk_h2(tv[4], tv[5]), pk_h2(tv[6], tv[7]));
      Zhi[zo] = pk_h2(tv[8], tv[9]);
    }
  }
}

// ---------------- fused conv + LSTM + factor update + next-iter prep ----------------
__global__ __launch_bounds__(256) void k_convlstm(const float* __restrict__ feat_c, float* __restrict__ H,
                                                  float* __restrict__ C, float* __restrict__ W,
                                                  const int* __restrict__ perm, const float* __restrict__ dinv,
                                                  float* __restrict__ feat, u32* __restrict__ Zlo,
                                                  u32* __restrict__ Zhi, const float* __restrict__ wts) {
  constexpr int NB = (NN + 255) / 256;  // 391
  int g = (blockIdx.x >= NB) ? 1 : 0;
  int n = (blockIdx.x - g * NB) * 256 + threadIdx.x;
  __shared__ float sigi[256 * 33];
  if (n >= NN) return;
  const float* Wc = wts + (g ? WOFF_WCH : WOFF_WCW);
  const float* bc = wts + (g ? WOFF_BCH : WOFF_BCW);
  const float* Wg = wts + (g ? WOFF_WGM : WOFF_WGU);
  const float* Ug = wts + (g ? WOFF_UGM : WOFF_UGU);
  const float* bg = wts + (g ? WOFF_BGM : WOFF_BGU);
  const float* Wo = wts + (g ? WOFF_WOH : WOFF_WOW);
  const float* bo = wts + (g ? WOFF_BOH : WOFF_BOW);
  // conv: xr = relu(feat[50] @ Wc + bc)
  const float* frow_c = feat_c + ((size_t)g * NN + n) * 60;
  float xr[32];
#pragma unroll
  for (int o = 0; o < 32; o++) xr[o] = bc[o];
#pragma unroll
  for (int k = 0; k < 5; k++) {
    const float4* f4 = (const float4*)(frow_c + k * 12);
    float4 a = f4[0], b2 = f4[1], c2 = f4[2];
    float fv[10] = {a.x, a.y, a.z, a.w, b2.x, b2.y, b2.z, b2.w, c2.x, c2.y};
#pragma unroll
    for (int j = 0; j < 10; j++) {
      const float* wr = Wc + (k * 10 + j) * 32;  // wave-uniform -> s_load
      float xv = fv[j];
#pragma unroll
      for (int o = 0; o < 32; o++) xr[o] += xv * wr[o];
    }
  }
#pragma unroll
  for (int o = 0; o < 32; o++) xr[o] = fmaxf(xr[o], 0.f);
  // lstm
  float* hp = H + ((size_t)g * NN + n) * 32;
  float* cp = C + ((size_t)g * NN + n) * 32;
  float hr[32], cr[32];
#pragma unroll
  for (int o = 0; o < 32; o += 4) {
    *(float4*)(hr + o) = *(const float4*)(hp + o);
    *(float4*)(cr + o) = *(const float4*)(cp + o);
  }
  float* si = &sigi[threadIdx.x * 33];
#pragma unroll 1
  for (int kk = 0; kk < 4; kk++) {  // f, i(->LDS), u, o
    int k = (kk == 0) ? 0 : (kk == 1) ? 1 : (kk == 2) ? 3 : 2;
    const float* wgk = Wg + k * 1024;
    const float* ugk = Ug + k * 1024;
    const float* bgk = bg + k * 32;
    float acc[32];
#pragma unroll
    for (int o = 0; o < 32; o++) acc[o] = bgk[o];
#pragma unroll
    for (int f = 0; f < 32; f++) {
      float xv = xr[f];
      const float* w = wgk + f * 32;
#pragma unroll
      for (int o = 0; o < 32; o++) acc[o] += xv * w[o];
    }
#pragma unroll
    for (int f = 0; f < 32; f++) {
      float hv = hr[f];
      const float* w = ugk + f * 32;
#pragma unroll
      for (int o = 0; o < 32; o++) acc[o] += hv * w[o];
    }
#pragma unroll
    for (int o = 0; o < 32; o++) acc[o] = sigf(acc[o]);
    if (kk == 0) {
#pragma unroll
      for (int o = 0; o < 32; o++) cr[o] *= acc[o];
    } else if (kk == 1) {
#pragma unroll
      for (int o = 0; o < 32; o++) si[o] = acc[o];
    } else if (kk == 2) {
#pragma unroll
      for (int o = 0; o < 32; o++) cr[o] += si[o] * acc[o];
    } else {
#pragma unroll
      for (int o = 0; o < 32; o++) hr[o] = acc[o] * sigf(cr[o]);  // h = o*sigmoid(c) (faithful)
    }
  }
#pragma unroll
  for (int o = 0; o < 32; o += 4) {
    *(float4*)(hp + o) = *(float4*)(hr + o);
    *(float4*)(cp + o) = *(float4*)(cr + o);
  }
  // W += tanh(h @ W_out + b_out); refresh feat slice0 + Z buf0
  float aw[10];
#pragma unroll
  for (int r = 0; r < 10; r++) aw[r] = bo[r];
#pragma unroll
  for (int f = 0; f < 32; f++) {
    float hv = hr[f];
    const float* w = Wo + f * 10;
#pragma unroll
    for (int r = 0; r < 10; r++) aw[r] += hv * w[r];
  }
  int row = perm[(size_t)g * GS + n];
  float dv = dinv[(size_t)g * GS + row];
  float* wrow = W + ((size_t)g * NN + row) * 12;
  float* frow = feat + ((size_t)g * NN + n) * 60;
  float zv[10];
#pragma unroll
  for (int r = 0; r < 10; r++) {
    float t = fminf(fmaxf(aw[r], -15.f), 15.f);
    float e = __expf(2.f * t);
    float th = (e - 1.f) / (e + 1.f);
    float wn = wrow[r] + th;
    wrow[r] = wn;
    frow[r] = wn;
    zv[r] = dv * wn;
  }
  size_t zo = ((size_t)g * 2 + 0) * NN + row;
  *(uint4*)(Zlo + zo * 4) = make_uint4(pk_h2(zv[0], zv[1]), pk_h2(zv[2], zv[3]),
                                       pk_h2(zv[4], zv[5]), pk_h2(zv[6], zv[7]));
  Zhi[zo] = pk_h2(zv[8], zv[9]);
}

// ---------------- scoring ----------------
__global__ __launch_bounds__(256) void k_score(const int* __restrict__ uid, const int* __restrict__ iid,
                                               const float* __restrict__ W, void* __restrict__ outp,
                                               const u32* __restrict__ flag) {
  int t = blockIdx.x * 256 + threadIdx.x;
  if (t >= 65536) return;
  int u = uid[t], i = iid[t];
  const float* wr = W + (size_t)u * 12;
  const float* hr = W + ((size_t)NN + i) * 12;
  float r = 0.f;
#pragma unroll
  for (int k = 0; k < 10; k++) r += wr[k] * hr[k];
  float v = 1.f + 4.f * sigf(r);
  if (flag[0]) ((u16*)outp)[t] = f2b(v);
  else         ((float*)outp)[t] = v;
}

// ---------------- host ----------------
extern "C" void kernel_launch(void* const* d_in, const int* in_sizes, int n_in,
                              void* d_out, int out_size, void* d_ws, size_t ws_size,
                              hipStream_t stream) {
  (void)in_sizes; (void)n_in; (void)out_size;
  if (ws_size < WS_NEED) return;

  const int* uid = (const int*)d_in[0];
  const int* iid = (const int*)d_in[1];
  const int* ur = (const int*)d_in[2];
  const int* uc = (const int*)d_in[3];
  const void* uv = d_in[4];
  const int* ir = (const int*)d_in[5];
  const int* ic = (const int*)d_in[6];
  const void* iv = d_in[7];

  char* ws = (char*)d_ws;
  u64* cntdeg = (u64*)(ws + OFF_CNTDEG);
  u32* dbin = (u32*)(ws + OFF_DBIN);
  u32* dfill = dbin + 512;
  u32* doff = dbin + 1024;
  int* bsum = (int*)(dbin + 1536);
  u32* flag = dbin + 2560;
  int* rps = (int*)(ws + OFF_RPS);
  int* fill = (int*)(ws + OFF_FILL);
  int* perm = (int*)(ws + OFF_PERM);
  int* islot = (int*)(ws + OFF_ISLOT);
  float* dinv = (float*)(ws + OFF_DINV);
  float* wts = (float*)(ws + OFF_WTS);
  float* W = (float*)(ws + OFF_W);
  u32* Zlo = (u32*)(ws + OFF_ZLO);
  u32* Zhi = (u32*)(ws + OFF_ZHI);
  float* feat = (float*)(ws + OFF_FEAT);
  float* H = (float*)(ws + OFF_H);
  float* C = (float*)(ws + OFF_C);
  u32* ce = (u32*)(ws + OFF_CE);

  // zero cntdeg + dbin + dfill (contiguous), and H+C (contiguous)
  hipMemsetAsync(ws, 0, OFF_DBIN + 4096, stream);
  hipMemsetAsync(ws + OFF_H, 0, (size_t)4 * NN * 32 * 4, stream);

  k_detect<<<1, 256, 0, stream>>>((const u16*)uv, flag);
  k_init<<<(2 * NN + 255) / 256, 256, 0, stream>>>(d_in[8], d_in[9], W, flag);
  k_hist<<<4096, 256, 0, stream>>>(ur, uv, ir, iv, cntdeg, flag);
  k_dcount<<<(2 * NN + 255) / 256, 256, 0, stream>>>(cntdeg, dbin);
  k_dscan<<<1, 512, 0, stream>>>(dbin, doff);
  k_dplace<<<(2 * NN + 255) / 256, 256, 0, stream>>>(cntdeg, doff, dfill, perm, islot, dinv);
  k_scan1<<<2 * NBPG, 256, 0, stream>>>(cntdeg, perm, rps, bsum);
  k_scan2<<<2, 512, 0, stream>>>(bsum);
  k_scan3<<<2 * NBPG, 256, 0, stream>>>(rps, fill, bsum);
  k_scatter<<<4096, 256, 0, stream>>>(ur, uc, uv, ir, ic, iv, islot, fill, ce, flag);
  P14 wp;
  for (int i = 0; i < 14; i++) wp.p[i] = d_in[10 + i];
  k_cvtw<<<(WTOTAL + 255) / 256, 256, 0, stream>>>(wp, wts, flag);
  k_prep<<<(2 * NN + 255) / 256, 256, 0, stream>>>(W, perm, dinv, feat, Zlo, Zhi);

  constexpr int NBG = (NN + 63) / 64;             // 1563
  constexpr int CHEB_GRID = 8 * ((NBG + 3) / 4);  // 3128, XCD-swizzled
  constexpr int NODE_GRID = 2 * ((NN + 255) / 256);
  for (int it = 0; it < 10; ++it) {
    k_cheb<1><<<CHEB_GRID, 256, 0, stream>>>(rps, ce, perm, dinv, feat, Zlo, Zhi);
    k_cheb<2><<<CHEB_GRID, 256, 0, stream>>>(rps, ce, perm, dinv, feat, Zlo, Zhi);
    k_cheb<3><<<CHEB_GRID, 256, 0, stream>>>(rps, ce, perm, dinv, feat, Zlo, Zhi);
    k_cheb<4><<<CHEB_GRID, 256, 0, stream>>>(rps, ce, perm, dinv, feat, Zlo, Zhi);
    k_convlstm<<<NODE_GRID, 256, 0, stream>>>(feat, H, C, W, perm, dinv, feat, Zlo, Zhi, wts);
  }
  k_score<<<256, 256, 0, stream>>>(uid, iid, W, d_out, flag);
}